// Round 2
// baseline (146.325 us; speedup 1.0000x reference)
//
#include <hip/hip_runtime.h>
#include <math.h>

#define GRIDN 28
#define NPTS 784
#define BATCH 128
#define TT 25
#define KMAX 2
#define FOUT 50
#define NCLS 10
#define M0F 0.05f

// Static device scratch (recomputed every call; deterministic).
__device__ int   g_sortedT[NPTS * NPTS];     // [rank][point], packed (d2<<10)|j
__device__ float g_f[BATCH * NPTS];          // dtm output
__device__ float g_land[BATCH * TT * KMAX];  // landscape features

// ---------------------------------------------------------------------------
// Kernel 1: per-point sorted neighbor table.
// Block = one grid point i; bitonic sort 1024 packed keys (pad = INT_MAX).
// d2 = (ix-jx)^2 + (iy-jy)^2  (integer, <= 1458, fits 11 bits; idx fits 10).
// Stored transposed so k_dtm reads are lane-coalesced.
// ---------------------------------------------------------------------------
__global__ __launch_bounds__(512) void k_sort() {
    __shared__ int keys[1024];
    const int i = blockIdx.x;
    const int ix = i / GRIDN, iy = i % GRIDN;
    for (int e = threadIdx.x; e < 1024; e += 512) {
        int v;
        if (e < NPTS) {
            int jx = e / GRIDN, jy = e % GRIDN;
            int dx = ix - jx, dy = iy - jy;
            int d2 = dx * dx + dy * dy;
            v = (d2 << 10) | e;
        } else {
            v = 0x7FFFFFFF;
        }
        keys[e] = v;
    }
    for (int k = 2; k <= 1024; k <<= 1) {
        for (int j = k >> 1; j > 0; j >>= 1) {
            __syncthreads();
            for (int t = threadIdx.x; t < 1024; t += 512) {
                int txj = t ^ j;
                if (txj > t) {
                    int a = keys[t], b = keys[txj];
                    bool up = ((t & k) == 0);
                    if ((a > b) == up) { keys[t] = b; keys[txj] = a; }
                }
            }
        }
    }
    __syncthreads();
    for (int e = threadIdx.x; e < NPTS; e += 512)
        g_sortedT[e * NPTS + i] = keys[e];
}

// ---------------------------------------------------------------------------
// Kernel 2: DTM with early exit. Block = one batch. w staged in LDS.
// term = (cum<bound) ? w : (prev<bound ? bound-prev : 0); stop once cum>=bound
// (weights are >=0 so all later terms are exactly 0).
// ---------------------------------------------------------------------------
__global__ __launch_bounds__(256) void k_dtm(const float* __restrict__ w) {
    __shared__ float wl[NPTS];
    __shared__ float red[256];
    const int b = blockIdx.x;
    float part = 0.f;
    for (int p = threadIdx.x; p < NPTS; p += 256) {
        float v = w[b * NPTS + p];
        wl[p] = v;
        part += v;
    }
    red[threadIdx.x] = part;
    __syncthreads();
    for (int s = 128; s > 0; s >>= 1) {
        if (threadIdx.x < s) red[threadIdx.x] += red[threadIdx.x + s];
        __syncthreads();
    }
    const float bound = M0F * red[0];
    for (int i = threadIdx.x; i < NPTS; i += 256) {
        float cum = 0.f, acc = 0.f;
        for (int r = 0; r < NPTS; ++r) {
            int packed = g_sortedT[r * NPTS + i];
            int idx = packed & 1023;
            float d2 = (float)(packed >> 10);
            float wj = wl[idx];
            float ncum = cum + wj;
            float term = (ncum < bound) ? wj
                        : ((cum < bound) ? (bound - cum) : 0.f);
            acc += term * d2;
            cum = ncum;
            if (cum >= bound) break;   // all remaining terms are 0
        }
        float dtm2 = acc / bound;
        g_f[b * NPTS + i] = sqrtf(fmaxf(dtm2, 0.f));
    }
}

// ---------------------------------------------------------------------------
// Kernel 3: landscape. Block = one batch (4 waves).
// d = 5-point neighborhood max (edge-clamped); tent = relu(min(t-f, d-t));
// per-(b,t) top-2 over 784 points via per-wave shuffle reduce.
// tent >= 0 always, so 0 is a safe top-2 identity.
// ---------------------------------------------------------------------------
__global__ __launch_bounds__(256) void k_land() {
    __shared__ float fl[NPTS];
    __shared__ float dl[NPTS];
    const int b = blockIdx.x;
    for (int p = threadIdx.x; p < NPTS; p += 256)
        fl[p] = g_f[b * NPTS + p];
    __syncthreads();
    for (int p = threadIdx.x; p < NPTS; p += 256) {
        int r = p / GRIDN, c = p % GRIDN;
        float up = fl[(r > 0 ? r - 1 : 0) * GRIDN + c];
        float dn = fl[(r < GRIDN - 1 ? r + 1 : GRIDN - 1) * GRIDN + c];
        float lf = fl[r * GRIDN + (c > 0 ? c - 1 : 0)];
        float rt = fl[r * GRIDN + (c < GRIDN - 1 ? c + 1 : GRIDN - 1)];
        float m = fmaxf(fmaxf(up, dn), fmaxf(lf, rt));
        dl[p] = fmaxf(m, fl[p]);
    }
    __syncthreads();
    const int wave = threadIdx.x >> 6;
    const int lane = threadIdx.x & 63;
    for (int t = wave; t < TT; t += 4) {
        float tv = (t == TT - 1) ? 2.0f : (float)t * (2.0f / (float)(TT - 1));
        float m1 = 0.f, m2 = 0.f;
        for (int p = lane; p < NPTS; p += 64) {
            float tent = fminf(tv - fl[p], dl[p] - tv);
            tent = fmaxf(tent, 0.f);
            if (tent > m1) { m2 = m1; m1 = tent; }
            else if (tent > m2) { m2 = tent; }
        }
        for (int off = 32; off > 0; off >>= 1) {
            float o1 = __shfl_xor(m1, off);
            float o2 = __shfl_xor(m2, off);
            float nm1 = fmaxf(m1, o1);
            float nm2 = fmaxf(fminf(m1, o1), fmaxf(m2, o2));
            m1 = nm1; m2 = nm2;
        }
        if (lane == 0) {
            g_land[b * (TT * KMAX) + 2 * t]     = m1;
            g_land[b * (TT * KMAX) + 2 * t + 1] = m2;
        }
    }
}

// ---------------------------------------------------------------------------
// Kernel 4: head. Single block. x1 = land@W_topo + b_topo (in LDS);
// signal = sum_b |x1|; batchnorm over batch (biased var, two-pass);
// out = relu(y) @ W_fc + b_fc. d_out = [out (128x10), signal (50)].
// ---------------------------------------------------------------------------
__global__ __launch_bounds__(256) void k_head(
        const float* __restrict__ W_topo, const float* __restrict__ b_topo,
        const float* __restrict__ gamma,  const float* __restrict__ beta,
        const float* __restrict__ W_fc,   const float* __restrict__ b_fc,
        float* __restrict__ out) {
    __shared__ float x1[BATCH * FOUT];
    __shared__ float smu[FOUT], srs[FOUT], sg[FOUT], sb[FOUT];
    for (int idx = threadIdx.x; idx < BATCH * FOUT; idx += 256) {
        int bb = idx / FOUT, ff = idx % FOUT;
        float s = b_topo[ff];
        const float* lrow = &g_land[bb * (TT * KMAX)];
        for (int k = 0; k < TT * KMAX; ++k)
            s += lrow[k] * W_topo[k * FOUT + ff];
        x1[idx] = s;
    }
    __syncthreads();
    if (threadIdx.x < FOUT) {
        int ff = threadIdx.x;
        float sab = 0.f, s = 0.f;
        for (int bb = 0; bb < BATCH; ++bb) {
            float v = x1[bb * FOUT + ff];
            sab += fabsf(v);
            s += v;
        }
        float mu = s / (float)BATCH;
        float v2 = 0.f;
        for (int bb = 0; bb < BATCH; ++bb) {
            float d = x1[bb * FOUT + ff] - mu;
            v2 += d * d;
        }
        float var = v2 / (float)BATCH;
        out[BATCH * NCLS + ff] = sab;          // signal
        smu[ff] = mu;
        srs[ff] = 1.0f / sqrtf(var + 1e-5f);
        sg[ff]  = gamma[ff];
        sb[ff]  = beta[ff];
    }
    __syncthreads();
    for (int idx = threadIdx.x; idx < BATCH * FOUT; idx += 256) {
        int ff = idx % FOUT;
        float y = sg[ff] * (x1[idx] - smu[ff]) * srs[ff] + sb[ff];
        x1[idx] = fmaxf(y, 0.f);
    }
    __syncthreads();
    for (int idx = threadIdx.x; idx < BATCH * NCLS; idx += 256) {
        int bb = idx / NCLS, cc = idx % NCLS;
        float s = b_fc[cc];
        for (int ff = 0; ff < FOUT; ++ff)
            s += x1[bb * FOUT + ff] * W_fc[ff * NCLS + cc];
        out[bb * NCLS + cc] = s;
    }
}

extern "C" void kernel_launch(void* const* d_in, const int* in_sizes, int n_in,
                              void* d_out, int out_size, void* d_ws, size_t ws_size,
                              hipStream_t stream) {
    const float* input  = (const float*)d_in[0];
    const float* W_topo = (const float*)d_in[1];
    const float* b_topo = (const float*)d_in[2];
    const float* gamma  = (const float*)d_in[3];
    const float* beta   = (const float*)d_in[4];
    const float* W_fc   = (const float*)d_in[5];
    const float* b_fc   = (const float*)d_in[6];
    float* out = (float*)d_out;

    k_sort<<<dim3(NPTS), dim3(512), 0, stream>>>();
    k_dtm <<<dim3(BATCH), dim3(256), 0, stream>>>(input);
    k_land<<<dim3(BATCH), dim3(256), 0, stream>>>();
    k_head<<<dim3(1), dim3(256), 0, stream>>>(W_topo, b_topo, gamma, beta,
                                              W_fc, b_fc, out);
}

// Round 3
// 39.163 us; speedup vs baseline: 3.7363x; 3.7363x over previous
//
#include <hip/hip_runtime.h>
#include <math.h>

#define GRIDN 28
#define NPTS 784
#define BATCH 128
#define TT 25
#define KMAX 2
#define FOUT 50
#define NCLS 10
#define M0F 0.05f
#define NOFF 3025          // 55*55 relative offsets (dx,dy in [-27,27])
#define D2MAX 1459         // d2 <= 2*27^2 = 1458

// ---------------------------------------------------------------------------
// Compile-time offset table: all (dx,dy) sorted ascending by d2 = dx^2+dy^2,
// ties broken by lex (dx,dy) == ascending neighbor index for any fixed point.
// Packed: (d2<<12) | ((dx+27)<<6) | (dy+27). Built via constexpr counting
// sort (stable in e => stable in lex order). Lives in __constant__ memory.
// ---------------------------------------------------------------------------
struct OffTab { int v[NOFF]; };

constexpr OffTab make_offtab() {
    OffTab t{};
    int cnt[D2MAX] = {};
    for (int e = 0; e < NOFF; ++e) {
        int dx = e / 55 - 27, dy = e % 55 - 27;
        cnt[dx * dx + dy * dy]++;
    }
    int base[D2MAX] = {};
    int s = 0;
    for (int d = 0; d < D2MAX; ++d) { base[d] = s; s += cnt[d]; }
    for (int e = 0; e < NOFF; ++e) {          // ascending e => stable ties
        int dxp = e / 55, dyp = e % 55;
        int dx = dxp - 27, dy = dyp - 27;
        int d2 = dx * dx + dy * dy;
        t.v[base[d2]++] = (d2 << 12) | (dxp << 6) | dyp;
    }
    return t;
}
__constant__ OffTab c_off = make_offtab();

// Inter-kernel scratch (fully rewritten every call; deterministic).
__device__ float g_land[BATCH * TT * KMAX];
__device__ float g_y[BATCH * FOUT];

// ---------------------------------------------------------------------------
// Kernel 1: fused DTM + landscape. One block (1024 thr, 16 waves) per batch.
// Phase A: stage w + offsets in LDS, block-reduce sum -> bound.
// Phase B: per-point early-exit scan over offsets (all reads from LDS).
// Phase C: 5-point neighborhood max.  Phase D: 25 tents, per-wave top-2.
// ---------------------------------------------------------------------------
__global__ __launch_bounds__(1024) void k_fused(const float* __restrict__ w) {
    __shared__ float wl[NPTS];
    __shared__ int   soff[NOFF];
    __shared__ float fl[NPTS];
    __shared__ float dl[NPTS];
    __shared__ float red[16];
    __shared__ float sbound;
    const int b = blockIdx.x;
    const int tid = threadIdx.x;

    for (int e = tid; e < NOFF; e += 1024) soff[e] = c_off.v[e];

    float v = 0.f;
    if (tid < NPTS) { v = w[b * NPTS + tid]; wl[tid] = v; }
    float s = v;
    for (int off = 32; off > 0; off >>= 1) s += __shfl_xor(s, off);
    if ((tid & 63) == 0) red[tid >> 6] = s;
    __syncthreads();
    if (tid < 64) {
        float r2 = (tid < 16) ? red[tid] : 0.f;
        for (int off = 8; off > 0; off >>= 1) r2 += __shfl_xor(r2, off);
        if (tid == 0) sbound = M0F * r2;
    }
    __syncthreads();
    const float bound = sbound;

    if (tid < NPTS) {
        const int ix = tid / GRIDN, iy = tid % GRIDN;
        float cum = 0.f, acc = 0.f;
        for (int r = 0; r < NOFF; ++r) {
            int pk = soff[r];                      // LDS broadcast read
            int jx = ix + ((pk >> 6) & 63) - 27;
            int jy = iy + (pk & 63) - 27;
            if ((unsigned)jx < GRIDN && (unsigned)jy < GRIDN) {
                float wj = wl[jx * GRIDN + jy];
                float ncum = cum + wj;
                float term = (ncum < bound) ? wj
                            : ((cum < bound) ? (bound - cum) : 0.f);
                acc += term * (float)(pk >> 12);
                cum = ncum;
                if (cum >= bound) break;           // all later terms exactly 0
            }
        }
        fl[tid] = sqrtf(fmaxf(acc / bound, 0.f));
    }
    __syncthreads();

    if (tid < NPTS) {
        int r = tid / GRIDN, c = tid % GRIDN;
        float up = fl[(r > 0 ? r - 1 : 0) * GRIDN + c];
        float dn = fl[(r < GRIDN - 1 ? r + 1 : GRIDN - 1) * GRIDN + c];
        float lf = fl[r * GRIDN + (c > 0 ? c - 1 : 0)];
        float rt = fl[r * GRIDN + (c < GRIDN - 1 ? c + 1 : GRIDN - 1)];
        dl[tid] = fmaxf(fmaxf(fmaxf(up, dn), fmaxf(lf, rt)), fl[tid]);
    }
    __syncthreads();

    const int wave = tid >> 6, lane = tid & 63;
    for (int t = wave; t < TT; t += 16) {
        float tv = (t == TT - 1) ? 2.0f : (float)t * (2.0f / (float)(TT - 1));
        float m1 = 0.f, m2 = 0.f;
        for (int p = lane; p < NPTS; p += 64) {
            float tent = fmaxf(fminf(tv - fl[p], dl[p] - tv), 0.f);
            if (tent > m1) { m2 = m1; m1 = tent; }
            else m2 = fmaxf(m2, tent);
        }
        for (int off = 32; off > 0; off >>= 1) {
            float o1 = __shfl_xor(m1, off), o2 = __shfl_xor(m2, off);
            float nm2 = fmaxf(fminf(m1, o1), fmaxf(m2, o2));
            m1 = fmaxf(m1, o1); m2 = nm2;
        }
        if (lane == 0) {
            g_land[b * (TT * KMAX) + 2 * t]     = m1;
            g_land[b * (TT * KMAX) + 2 * t + 1] = m2;
        }
    }
}

// ---------------------------------------------------------------------------
// Kernel 2: head part 1. One block per output feature ff (50 blocks, 128 thr,
// thread = batch row). x1 = land@W_topo + b_topo; signal = sum|x1|;
// two-pass batchnorm stats via shuffle-tree reductions; g_y = relu(y).
// ---------------------------------------------------------------------------
__global__ __launch_bounds__(128) void k_head1(
        const float* __restrict__ W_topo, const float* __restrict__ b_topo,
        const float* __restrict__ gamma,  const float* __restrict__ beta,
        float* __restrict__ out) {
    __shared__ float ld[BATCH * TT * KMAX];
    __shared__ float wt[TT * KMAX];
    __shared__ float r0[2], r1[2], r2[2];
    const int ff = blockIdx.x;
    const int bb = threadIdx.x;

    for (int e = bb; e < BATCH * TT * KMAX; e += 128) ld[e] = g_land[e];
    if (bb < TT * KMAX) wt[bb] = W_topo[bb * FOUT + ff];
    __syncthreads();

    float s = b_topo[ff];
    #pragma unroll
    for (int k = 0; k < TT * KMAX; ++k) s += ld[bb * (TT * KMAX) + k] * wt[k];

    float su = s, sa = fabsf(s);
    for (int off = 32; off > 0; off >>= 1) {
        su += __shfl_xor(su, off);
        sa += __shfl_xor(sa, off);
    }
    if ((bb & 63) == 0) { r0[bb >> 6] = su; r1[bb >> 6] = sa; }
    __syncthreads();
    const float mu = (r0[0] + r0[1]) / (float)BATCH;
    if (bb == 0) out[BATCH * NCLS + ff] = r1[0] + r1[1];   // signal

    float d = s - mu, dv = d * d;
    for (int off = 32; off > 0; off >>= 1) dv += __shfl_xor(dv, off);
    if ((bb & 63) == 0) r2[bb >> 6] = dv;
    __syncthreads();
    const float var = (r2[0] + r2[1]) / (float)BATCH;

    float y = gamma[ff] * d * (1.0f / sqrtf(var + 1e-5f)) + beta[ff];
    g_y[bb * FOUT + ff] = fmaxf(y, 0.f);
}

// ---------------------------------------------------------------------------
// Kernel 3: head part 2. out = relu_y @ W_fc + b_fc (128x10).
// ---------------------------------------------------------------------------
__global__ __launch_bounds__(256) void k_head2(
        const float* __restrict__ W_fc, const float* __restrict__ b_fc,
        float* __restrict__ out) {
    __shared__ float wfc[FOUT * NCLS];
    for (int e = threadIdx.x; e < FOUT * NCLS; e += 256) wfc[e] = W_fc[e];
    __syncthreads();
    const int tid = blockIdx.x * 256 + threadIdx.x;
    if (tid < BATCH * NCLS) {
        int bb = tid / NCLS, cc = tid % NCLS;
        float s = b_fc[cc];
        #pragma unroll
        for (int f = 0; f < FOUT; ++f)
            s += g_y[bb * FOUT + f] * wfc[f * NCLS + cc];
        out[tid] = s;
    }
}

extern "C" void kernel_launch(void* const* d_in, const int* in_sizes, int n_in,
                              void* d_out, int out_size, void* d_ws, size_t ws_size,
                              hipStream_t stream) {
    const float* input  = (const float*)d_in[0];
    const float* W_topo = (const float*)d_in[1];
    const float* b_topo = (const float*)d_in[2];
    const float* gamma  = (const float*)d_in[3];
    const float* beta   = (const float*)d_in[4];
    const float* W_fc   = (const float*)d_in[5];
    const float* b_fc   = (const float*)d_in[6];
    float* out = (float*)d_out;

    k_fused<<<dim3(BATCH), dim3(1024), 0, stream>>>(input);
    k_head1<<<dim3(FOUT), dim3(128), 0, stream>>>(W_topo, b_topo, gamma, beta, out);
    k_head2<<<dim3((BATCH * NCLS + 255) / 256), dim3(256), 0, stream>>>(W_fc, b_fc, out);
}

// Round 4
// 29.911 us; speedup vs baseline: 4.8920x; 1.3093x over previous
//
#include <hip/hip_runtime.h>
#include <math.h>

#define GRIDN 28
#define NPTS 784
#define BATCH 128
#define TT 25
#define KMAX 2
#define FOUT 50
#define NCLS 10
#define M0F 0.05f
#define NOFF 3025          // 55*55 relative offsets (dx,dy in [-27,27])
#define NOFFP 3032         // padded to multiple of 8 with invalid sentinels
#define D2MAX 1459         // d2 <= 2*27^2 = 1458

// ---------------------------------------------------------------------------
// Compile-time offset table: all (dx,dy) sorted ascending by d2 = dx^2+dy^2,
// ties broken by lex (dx,dy) == ascending neighbor index for any fixed point
// (bit-identical visit order to the verified round-2 kernel).
// Packed: (d2<<12) | ((dx+27)<<6) | (dy+27). Constexpr counting sort.
// Padding entries have dx+27=63 -> always out of bounds -> wj=0 (no-op).
// ---------------------------------------------------------------------------
struct OffTab { int v[NOFFP]; };

constexpr OffTab make_offtab() {
    OffTab t{};
    int cnt[D2MAX] = {};
    for (int e = 0; e < NOFF; ++e) {
        int dx = e / 55 - 27, dy = e % 55 - 27;
        cnt[dx * dx + dy * dy]++;
    }
    int base[D2MAX] = {};
    int s = 0;
    for (int d = 0; d < D2MAX; ++d) { base[d] = s; s += cnt[d]; }
    for (int e = 0; e < NOFF; ++e) {          // ascending e => stable ties
        int dxp = e / 55, dyp = e % 55;
        int dx = dxp - 27, dy = dyp - 27;
        int d2 = dx * dx + dy * dy;
        t.v[base[d2]++] = (d2 << 12) | (dxp << 6) | dyp;
    }
    for (int e = NOFF; e < NOFFP; ++e) t.v[e] = (63 << 6) | 63;
    return t;
}
__constant__ OffTab c_off = make_offtab();

// Inter-kernel scratch (fully rewritten every call; deterministic).
__device__ float g_x1[BATCH * FOUT];

// ---------------------------------------------------------------------------
// Kernel 1: fused DTM + landscape + topo-GEMM. One 1024-thr block per batch.
// Phase A: stage w in LDS, block-reduce sum -> bound.
// Phase B: per-point chunked (8-wide) early-exit scan; offsets come straight
//          from __constant__ via uniform-index scalar loads; 8 independent
//          LDS weight reads per chunk hide LDS latency.
//          term = min(max(bound-cum,0), wj)  (exact rewrite; wj=0 for OOB).
// Phase C: 5-point neighborhood max.
// Phase D: 25 tents, per-wave top-2 -> sland[50] (LDS).
// Phase E: x1[b][:] = sland @ W_topo + b_topo -> g_x1.
// ---------------------------------------------------------------------------
__global__ __launch_bounds__(1024) void k_fused(
        const float* __restrict__ w,
        const float* __restrict__ W_topo, const float* __restrict__ b_topo) {
    __shared__ float wl[NPTS];
    __shared__ float fl[NPTS];
    __shared__ float dl[NPTS];
    __shared__ float sland[TT * KMAX];
    __shared__ float red[16];
    __shared__ float sbound;
    const int b = blockIdx.x;
    const int tid = threadIdx.x;

    // Phase A
    float v = 0.f;
    if (tid < NPTS) { v = w[b * NPTS + tid]; wl[tid] = v; }
    float s = v;
    for (int off = 32; off > 0; off >>= 1) s += __shfl_xor(s, off);
    if ((tid & 63) == 0) red[tid >> 6] = s;
    __syncthreads();
    if (tid < 64) {
        float r2 = (tid < 16) ? red[tid] : 0.f;
        for (int off = 8; off > 0; off >>= 1) r2 += __shfl_xor(r2, off);
        if (tid == 0) sbound = M0F * r2;
    }
    __syncthreads();
    const float bound = sbound;

    // Phase B
    if (tid < NPTS) {
        const int ix = tid / GRIDN, iy = tid % GRIDN;
        float cum = 0.f, acc = 0.f;
        for (int r = 0; r < NOFFP; r += 8) {
            int pk[8];
            #pragma unroll
            for (int u = 0; u < 8; ++u) pk[u] = c_off.v[r + u]; // scalar loads
            float wj[8];
            #pragma unroll
            for (int u = 0; u < 8; ++u) {                       // 8 indep LDS reads
                int jx = ix + ((pk[u] >> 6) & 63) - 27;
                int jy = iy + (pk[u] & 63) - 27;
                bool valid = ((unsigned)jx < (unsigned)GRIDN) &
                             ((unsigned)jy < (unsigned)GRIDN);
                int j = valid ? (jx * GRIDN + jy) : 0;
                wj[u] = valid ? wl[j] : 0.f;
            }
            #pragma unroll
            for (int u = 0; u < 8; ++u) {                       // register-only
                float t = fminf(fmaxf(bound - cum, 0.f), wj[u]);
                acc += t * (float)(pk[u] >> 12);
                cum += wj[u];
            }
            if (cum >= bound) break;     // all later terms exactly 0
        }
        fl[tid] = sqrtf(fmaxf(acc / bound, 0.f));
    }
    __syncthreads();

    // Phase C
    if (tid < NPTS) {
        int r = tid / GRIDN, c = tid % GRIDN;
        float up = fl[(r > 0 ? r - 1 : 0) * GRIDN + c];
        float dn = fl[(r < GRIDN - 1 ? r + 1 : GRIDN - 1) * GRIDN + c];
        float lf = fl[r * GRIDN + (c > 0 ? c - 1 : 0)];
        float rt = fl[r * GRIDN + (c < GRIDN - 1 ? c + 1 : GRIDN - 1)];
        dl[tid] = fmaxf(fmaxf(fmaxf(up, dn), fmaxf(lf, rt)), fl[tid]);
    }
    __syncthreads();

    // Phase D
    const int wave = tid >> 6, lane = tid & 63;
    for (int t = wave; t < TT; t += 16) {
        float tv = (t == TT - 1) ? 2.0f : (float)t * (2.0f / (float)(TT - 1));
        float m1 = 0.f, m2 = 0.f;
        for (int p = lane; p < NPTS; p += 64) {
            float tent = fmaxf(fminf(tv - fl[p], dl[p] - tv), 0.f);
            if (tent > m1) { m2 = m1; m1 = tent; }
            else m2 = fmaxf(m2, tent);
        }
        for (int off = 32; off > 0; off >>= 1) {
            float o1 = __shfl_xor(m1, off), o2 = __shfl_xor(m2, off);
            float nm2 = fmaxf(fminf(m1, o1), fmaxf(m2, o2));
            m1 = fmaxf(m1, o1); m2 = nm2;
        }
        if (lane == 0) {
            sland[2 * t]     = m1;
            sland[2 * t + 1] = m2;
        }
    }
    __syncthreads();

    // Phase E
    if (tid < FOUT) {
        float acc = b_topo[tid];
        #pragma unroll
        for (int k = 0; k < TT * KMAX; ++k)
            acc += sland[k] * W_topo[k * FOUT + tid];
        g_x1[b * FOUT + tid] = acc;
    }
}

// ---------------------------------------------------------------------------
// Kernel 2: batchnorm + head, one 1024-thr block.
// Stats per feature via 16-lane shuffle groups (f = tid>>4, sub = tid&15,
// each sub owns 8 batch rows kept in registers for the two-pass var).
// signal = sum_b |x1|; relu(y) written back to LDS; out = relu_y @ W_fc + b_fc.
// d_out = [out (128x10), signal (50)].
// ---------------------------------------------------------------------------
__global__ __launch_bounds__(1024) void k_bnhead(
        const float* __restrict__ gamma, const float* __restrict__ beta,
        const float* __restrict__ W_fc,  const float* __restrict__ b_fc,
        float* __restrict__ out) {
    __shared__ float x1l[BATCH * FOUT];
    __shared__ float wfc[FOUT * NCLS];
    const int tid = threadIdx.x;

    for (int e = tid; e < BATCH * FOUT; e += 1024) x1l[e] = g_x1[e];
    if (tid < FOUT * NCLS) wfc[tid] = W_fc[tid];
    __syncthreads();

    if (tid < FOUT * 16) {
        const int f = tid >> 4, sub = tid & 15;
        float vals[8];
        float su = 0.f, sa = 0.f;
        #pragma unroll
        for (int k = 0; k < 8; ++k) {
            float v = x1l[(sub + 16 * k) * FOUT + f];
            vals[k] = v;
            su += v;
            sa += fabsf(v);
        }
        #pragma unroll
        for (int off = 8; off > 0; off >>= 1) {
            su += __shfl_xor(su, off);
            sa += __shfl_xor(sa, off);
        }
        const float mu = su * (1.0f / (float)BATCH);
        if (sub == 0) out[BATCH * NCLS + f] = sa;          // signal
        float dv = 0.f;
        #pragma unroll
        for (int k = 0; k < 8; ++k) {
            float d = vals[k] - mu;
            dv += d * d;
        }
        #pragma unroll
        for (int off = 8; off > 0; off >>= 1) dv += __shfl_xor(dv, off);
        const float var = dv * (1.0f / (float)BATCH);
        const float rstd = 1.0f / sqrtf(var + 1e-5f);
        const float g = gamma[f], be = beta[f];
        #pragma unroll
        for (int k = 0; k < 8; ++k) {
            float y = g * (vals[k] - mu) * rstd + be;
            x1l[(sub + 16 * k) * FOUT + f] = fmaxf(y, 0.f);
        }
    }
    __syncthreads();

    for (int idx = tid; idx < BATCH * NCLS; idx += 1024) {
        const int bb = idx / NCLS, cc = idx % NCLS;
        float s = b_fc[cc];
        #pragma unroll
        for (int f = 0; f < FOUT; ++f)
            s += x1l[bb * FOUT + f] * wfc[f * NCLS + cc];
        out[idx] = s;
    }
}

extern "C" void kernel_launch(void* const* d_in, const int* in_sizes, int n_in,
                              void* d_out, int out_size, void* d_ws, size_t ws_size,
                              hipStream_t stream) {
    const float* input  = (const float*)d_in[0];
    const float* W_topo = (const float*)d_in[1];
    const float* b_topo = (const float*)d_in[2];
    const float* gamma  = (const float*)d_in[3];
    const float* beta   = (const float*)d_in[4];
    const float* W_fc   = (const float*)d_in[5];
    const float* b_fc   = (const float*)d_in[6];
    float* out = (float*)d_out;

    k_fused<<<dim3(BATCH), dim3(1024), 0, stream>>>(input, W_topo, b_topo);
    k_bnhead<<<dim3(1), dim3(1024), 0, stream>>>(gamma, beta, W_fc, b_fc, out);
}

// Round 5
// 28.850 us; speedup vs baseline: 5.0719x; 1.0368x over previous
//
#include <hip/hip_runtime.h>
#include <math.h>

#define GRIDN 28
#define NPTS 784
#define BATCH 128
#define TT 25
#define KMAX 2
#define FOUT 50
#define NCLS 10
#define M0F 0.05f
#define NOFF 3025          // 55*55 relative offsets (dx,dy in [-27,27])
#define NOFFP 3032         // padded to multiple of 8 with invalid sentinels
#define D2MAX 1459         // d2 <= 2*27^2 = 1458
#define NSUB 8             // dtm sub-blocks per batch
#define PPS (NPTS / NSUB)  // 98 points per sub-block

// ---------------------------------------------------------------------------
// Compile-time offset table: all (dx,dy) sorted ascending by d2 = dx^2+dy^2,
// ties broken by lex (dx,dy) == ascending neighbor index for any fixed point
// (bit-identical visit order to the verified round-2/3 kernels).
// Packed: (d2<<12) | ((dx+27)<<6) | (dy+27). Constexpr counting sort.
// Padding entries have dx+27=63 -> always out of bounds -> wj=0 (no-op).
// ---------------------------------------------------------------------------
struct OffTab { int v[NOFFP]; };

constexpr OffTab make_offtab() {
    OffTab t{};
    int cnt[D2MAX] = {};
    for (int e = 0; e < NOFF; ++e) {
        int dx = e / 55 - 27, dy = e % 55 - 27;
        cnt[dx * dx + dy * dy]++;
    }
    int base[D2MAX] = {};
    int s = 0;
    for (int d = 0; d < D2MAX; ++d) { base[d] = s; s += cnt[d]; }
    for (int e = 0; e < NOFF; ++e) {          // ascending e => stable ties
        int dxp = e / 55, dyp = e % 55;
        int dx = dxp - 27, dy = dyp - 27;
        int d2 = dx * dx + dy * dy;
        t.v[base[d2]++] = (d2 << 12) | (dxp << 6) | dyp;
    }
    for (int e = NOFF; e < NOFFP; ++e) t.v[e] = (63 << 6) | 63;
    return t;
}
__constant__ OffTab c_off = make_offtab();

// Inter-kernel scratch (fully rewritten every call; deterministic).
__device__ float g_f[BATCH * NPTS];
__device__ float g_x1[BATCH * FOUT];

// ---------------------------------------------------------------------------
// Kernel 1: DTM scan, 8 sub-blocks per batch (1024 blocks x 128 thr -> full
// GPU, ~4 blocks/CU). Each sub-block stages w in LDS, recomputes bound with
// a fixed reduction shape (identical across sub-blocks), scans its 98 points
// with the 8-wide chunked early-exit loop (offsets from __constant__ via
// uniform scalar loads; term = min(max(bound-cum,0), wj), wj=0 for OOB).
// ---------------------------------------------------------------------------
__global__ __launch_bounds__(128) void k_dtm(const float* __restrict__ w) {
    __shared__ float wl[NPTS];
    __shared__ float red[2];
    const int b   = blockIdx.x >> 3;
    const int sub = blockIdx.x & 7;
    const int tid = threadIdx.x;

    float s = 0.f;
    for (int p = tid; p < NPTS; p += 128) {
        float v = w[b * NPTS + p];
        wl[p] = v;
        s += v;
    }
    for (int off = 32; off > 0; off >>= 1) s += __shfl_xor(s, off);
    if ((tid & 63) == 0) red[tid >> 6] = s;
    __syncthreads();
    const float bound = M0F * (red[0] + red[1]);

    if (tid < PPS) {
        const int p = sub * PPS + tid;
        const int ix = p / GRIDN, iy = p % GRIDN;
        float cum = 0.f, acc = 0.f;
        for (int r = 0; r < NOFFP; r += 8) {
            int pk[8];
            #pragma unroll
            for (int u = 0; u < 8; ++u) pk[u] = c_off.v[r + u]; // scalar loads
            float wj[8];
            #pragma unroll
            for (int u = 0; u < 8; ++u) {                       // 8 indep LDS reads
                int jx = ix + ((pk[u] >> 6) & 63) - 27;
                int jy = iy + (pk[u] & 63) - 27;
                bool valid = ((unsigned)jx < (unsigned)GRIDN) &
                             ((unsigned)jy < (unsigned)GRIDN);
                int j = valid ? (jx * GRIDN + jy) : 0;
                wj[u] = valid ? wl[j] : 0.f;
            }
            #pragma unroll
            for (int u = 0; u < 8; ++u) {                       // register-only
                float t = fminf(fmaxf(bound - cum, 0.f), wj[u]);
                acc += t * (float)(pk[u] >> 12);
                cum += wj[u];
            }
            if (cum >= bound) break;     // all later terms exactly 0
        }
        g_f[b * NPTS + p] = sqrtf(fmaxf(acc / bound, 0.f));
    }
}

// ---------------------------------------------------------------------------
// Kernel 2: landscape + topo-GEMM. One 1024-thr block per batch.
// Phase C: 5-point neighborhood max.
// Phase D: 25 tents, per-wave top-2 -> sland[50] (LDS).
// Phase E: x1[b][:] = sland @ W_topo + b_topo -> g_x1.
// ---------------------------------------------------------------------------
__global__ __launch_bounds__(1024) void k_land(
        const float* __restrict__ W_topo, const float* __restrict__ b_topo) {
    __shared__ float fl[NPTS];
    __shared__ float dl[NPTS];
    __shared__ float sland[TT * KMAX];
    const int b = blockIdx.x;
    const int tid = threadIdx.x;

    if (tid < NPTS) fl[tid] = g_f[b * NPTS + tid];
    __syncthreads();

    if (tid < NPTS) {
        int r = tid / GRIDN, c = tid % GRIDN;
        float up = fl[(r > 0 ? r - 1 : 0) * GRIDN + c];
        float dn = fl[(r < GRIDN - 1 ? r + 1 : GRIDN - 1) * GRIDN + c];
        float lf = fl[r * GRIDN + (c > 0 ? c - 1 : 0)];
        float rt = fl[r * GRIDN + (c < GRIDN - 1 ? c + 1 : GRIDN - 1)];
        dl[tid] = fmaxf(fmaxf(fmaxf(up, dn), fmaxf(lf, rt)), fl[tid]);
    }
    __syncthreads();

    const int wave = tid >> 6, lane = tid & 63;
    for (int t = wave; t < TT; t += 16) {
        float tv = (t == TT - 1) ? 2.0f : (float)t * (2.0f / (float)(TT - 1));
        float m1 = 0.f, m2 = 0.f;
        for (int p = lane; p < NPTS; p += 64) {
            float tent = fmaxf(fminf(tv - fl[p], dl[p] - tv), 0.f);
            if (tent > m1) { m2 = m1; m1 = tent; }
            else m2 = fmaxf(m2, tent);
        }
        for (int off = 32; off > 0; off >>= 1) {
            float o1 = __shfl_xor(m1, off), o2 = __shfl_xor(m2, off);
            float nm2 = fmaxf(fminf(m1, o1), fmaxf(m2, o2));
            m1 = fmaxf(m1, o1); m2 = nm2;
        }
        if (lane == 0) {
            sland[2 * t]     = m1;
            sland[2 * t + 1] = m2;
        }
    }
    __syncthreads();

    if (tid < FOUT) {
        float acc = b_topo[tid];
        #pragma unroll
        for (int k = 0; k < TT * KMAX; ++k)
            acc += sland[k] * W_topo[k * FOUT + tid];
        g_x1[b * FOUT + tid] = acc;
    }
}

// ---------------------------------------------------------------------------
// Kernel 3: batchnorm + head, one 1024-thr block.
// Stats per feature via 16-lane shuffle groups (f = tid>>4, sub = tid&15,
// each sub owns 8 batch rows kept in registers for the two-pass var).
// signal = sum_b |x1|; relu(y) written back to LDS; out = relu_y @ W_fc + b_fc.
// d_out = [out (128x10), signal (50)].
// ---------------------------------------------------------------------------
__global__ __launch_bounds__(1024) void k_bnhead(
        const float* __restrict__ gamma, const float* __restrict__ beta,
        const float* __restrict__ W_fc,  const float* __restrict__ b_fc,
        float* __restrict__ out) {
    __shared__ float x1l[BATCH * FOUT];
    __shared__ float wfc[FOUT * NCLS];
    const int tid = threadIdx.x;

    for (int e = tid; e < BATCH * FOUT; e += 1024) x1l[e] = g_x1[e];
    if (tid < FOUT * NCLS) wfc[tid] = W_fc[tid];
    __syncthreads();

    if (tid < FOUT * 16) {
        const int f = tid >> 4, sub = tid & 15;
        float vals[8];
        float su = 0.f, sa = 0.f;
        #pragma unroll
        for (int k = 0; k < 8; ++k) {
            float v = x1l[(sub + 16 * k) * FOUT + f];
            vals[k] = v;
            su += v;
            sa += fabsf(v);
        }
        #pragma unroll
        for (int off = 8; off > 0; off >>= 1) {
            su += __shfl_xor(su, off);
            sa += __shfl_xor(sa, off);
        }
        const float mu = su * (1.0f / (float)BATCH);
        if (sub == 0) out[BATCH * NCLS + f] = sa;          // signal
        float dv = 0.f;
        #pragma unroll
        for (int k = 0; k < 8; ++k) {
            float d = vals[k] - mu;
            dv += d * d;
        }
        #pragma unroll
        for (int off = 8; off > 0; off >>= 1) dv += __shfl_xor(dv, off);
        const float var = dv * (1.0f / (float)BATCH);
        const float rstd = 1.0f / sqrtf(var + 1e-5f);
        const float g = gamma[f], be = beta[f];
        #pragma unroll
        for (int k = 0; k < 8; ++k) {
            float y = g * (vals[k] - mu) * rstd + be;
            x1l[(sub + 16 * k) * FOUT + f] = fmaxf(y, 0.f);
        }
    }
    __syncthreads();

    for (int idx = tid; idx < BATCH * NCLS; idx += 1024) {
        const int bb = idx / NCLS, cc = idx % NCLS;
        float s = b_fc[cc];
        #pragma unroll
        for (int f = 0; f < FOUT; ++f)
            s += x1l[bb * FOUT + f] * wfc[f * NCLS + cc];
        out[idx] = s;
    }
}

extern "C" void kernel_launch(void* const* d_in, const int* in_sizes, int n_in,
                              void* d_out, int out_size, void* d_ws, size_t ws_size,
                              hipStream_t stream) {
    const float* input  = (const float*)d_in[0];
    const float* W_topo = (const float*)d_in[1];
    const float* b_topo = (const float*)d_in[2];
    const float* gamma  = (const float*)d_in[3];
    const float* beta   = (const float*)d_in[4];
    const float* W_fc   = (const float*)d_in[5];
    const float* b_fc   = (const float*)d_in[6];
    float* out = (float*)d_out;

    k_dtm   <<<dim3(BATCH * NSUB), dim3(128), 0, stream>>>(input);
    k_land  <<<dim3(BATCH), dim3(1024), 0, stream>>>(W_topo, b_topo);
    k_bnhead<<<dim3(1), dim3(1024), 0, stream>>>(gamma, beta, W_fc, b_fc, out);
}